// Round 2
// baseline (254.655 us; speedup 1.0000x reference)
//
#include <hip/hip_runtime.h>

// YOLO loss: S=14, B=2, C=20, N_CH=30, batch=4096
// pred, target: (4096, 14, 14, 30) float32. Output: scalar float32.
//
// R7: R6 (box-only LDS staging for occupancy) failed nondeterministically;
// prime suspect was the cross-tile mtab prefetch (global strided mask read
// racing the barrier structure). This version derives the mask IN-STREAM:
// the float4 owning target-ch4 (rm==1 -> .x for even cells, rm==8 -> .z for
// odd cells) writes mtab; class contributions are summed masklessly per
// float4 (s_j, registers) and multiplied by mtab[cell0_j] after the barrier.
// All LDS state lives strictly inside one barrier-delimited iteration.
// Occupancy theory unchanged: 10.75 KiB LDS/block -> ~12 blocks/CU
// = 24 waves/CU (vs R5's 10), all global reads lane-contiguous float4.

#define SDIM 14
#define NCH  30
#define BATCH 4096
#define NCELLS (BATCH * SDIM * SDIM)      // 802816
#define TILE_CELLS 128
#define NTILES (NCELLS / TILE_CELLS)      // 6272, exact
#define TPB 2                             // tiles per block
#define NBLOCKS (NTILES / TPB)            // 3136
#define THREADS 128
#define TILE_F4 (TILE_CELLS * NCH / 4)    // 960 float4 per tensor per tile
#define L_COORD 5.0f
#define L_NOOBJ 0.5f

__global__ __launch_bounds__(THREADS, 6) void yolo_loss_stage1(
    const float* __restrict__ pred,
    const float* __restrict__ tgt,
    float* __restrict__ partial)
{
    // Box channels only: 128 cells x 10 ch x 4 B x 2 tensors = 10240 B.
    __shared__ __align__(16) float pbox[TILE_CELLS * 10];
    __shared__ __align__(16) float tbox[TILE_CELLS * 10];
    __shared__ float mtab[TILE_CELLS];    // m(cell), written in-stream each tile
    __shared__ float wsum[2];

    const int tid = threadIdx.x;
    const size_t tile0 = (size_t)blockIdx.x * TPB;

    float acc = 0.0f;

    for (int it = 0; it < TPB; ++it) {
        const size_t base = (tile0 + it) * (size_t)(TILE_CELLS * NCH);
        const float4* gp4 = (const float4*)(pred + base);
        const float4* gt4 = (const float4*)(tgt + base);

        // ---- P2: lane-contiguous float4 stream of BOTH tensors.
        // float4 #k covers flat floats 4k..4k+3; cell = f/30, ch = f%30.
        // k = 15q + rm  ->  cell0 = 2q + (rm>=8),  r = 4*rm - 30*(rm>=8).
        // Only rm==7 (r==28) straddles a cell; wrapped elements are ch 0/1
        // (box) of cell0+1, so class elements ALWAYS belong to cell0.
        float sj[8];
        #pragma unroll
        for (int j = 0; j < 8; ++j) sj[j] = 0.0f;

        #pragma unroll
        for (int j = 0; j < 8; ++j) {
            int k = j * THREADS + tid;
            if (k < TILE_F4) {                      // j==7: only tid<64 active
                float4 p4  = gp4[k];
                float4 t4v = gt4[k];
                int q  = k / 15;
                int rm = k - q * 15;
                int hi = (rm >= 8) ? 1 : 0;
                int cell0 = 2 * q + hi;
                int r = 4 * rm - 30 * hi;           // even, 0..28

                // Mask owners (one unique writer per cell):
                // even cell ch4 = rm1 elem .x ; odd cell ch4 = rm8 elem .z
                if (rm == 1) mtab[cell0] = (t4v.x > 0.0f) ? 1.0f : 0.0f;
                if (rm == 8) mtab[cell0] = (t4v.z > 0.0f) ? 1.0f : 0.0f;

                float pe[4] = {p4.x, p4.y, p4.z, p4.w};
                float te[4] = {t4v.x, t4v.y, t4v.z, t4v.w};
                float s = 0.0f;
                #pragma unroll
                for (int e = 0; e < 4; ++e) {
                    int ch = r + e;
                    int cell = cell0;
                    if (ch >= NCH) { ch -= NCH; cell += 1; }   // wrap -> box ch 0/1
                    if (ch < 10) {
                        pbox[cell * 10 + ch] = pe[e];
                        tbox[cell * 10 + ch] = te[e];
                    } else {
                        float d = pe[e] - te[e];
                        s = fmaf(d, d, s);          // maskless class partial
                    }
                }
                sj[j] = s;
            }
        }
        __syncthreads();   // scatter + mask table complete

        // ---- P2b: deferred class loss, mask applied from mtab.
        #pragma unroll
        for (int j = 0; j < 8; ++j) {
            int k = j * THREADS + tid;
            if (k < TILE_F4) {
                int q  = k / 15;
                int rm = k - q * 15;
                int cell0 = 2 * q + ((rm >= 8) ? 1 : 0);
                acc = fmaf(mtab[cell0], sj[j], acc);
            }
        }

        // ---- P3: per-cell box/obj/noobj math; thread tid owns cell tid.
        {
            float pv[10], tv[10];
            const float2* lp = (const float2*)(pbox + tid * 10);  // 8B-aligned
            const float2* lt = (const float2*)(tbox + tid * 10);
            #pragma unroll
            for (int i = 0; i < 5; ++i) {
                float2 a = lp[i]; pv[2*i] = a.x; pv[2*i+1] = a.y;
                float2 b = lt[i]; tv[2*i] = b.x; tv[2*i+1] = b.y;
            }

            const float invS = 1.0f / (float)SDIM;
            float m  = (tv[4] > 0.0f) ? 1.0f : 0.0f;
            float nm = 1.0f - m;

            // target box 0 -> xyxy
            float tcx = tv[0] * invS, tcy = tv[1] * invS;
            float tw  = tv[2],        th  = tv[3];
            float tx1 = tcx - 0.5f * tw, ty1 = tcy - 0.5f * th;
            float tx2 = tcx + 0.5f * tw, ty2 = tcy + 0.5f * th;
            float ta  = (tx2 - tx1) * (ty2 - ty1);

            float iou[2];
            #pragma unroll
            for (int b = 0; b < 2; ++b) {
                float cx = pv[5*b + 0] * invS, cy = pv[5*b + 1] * invS;
                float w  = pv[5*b + 2],        h  = pv[5*b + 3];
                float x1 = cx - 0.5f * w, y1 = cy - 0.5f * h;
                float x2 = cx + 0.5f * w, y2 = cy + 0.5f * h;
                float lx = fmaxf(x1, tx1), ly = fmaxf(y1, ty1);
                float rx = fminf(x2, tx2), ry = fminf(y2, ty2);
                float iw = fmaxf(rx - lx, 0.0f);
                float ih = fmaxf(ry - ly, 0.0f);
                float inter = iw * ih;
                float pa = (x2 - x1) * (y2 - y1);
                iou[b] = inter / (pa + ta - inter);
            }

            int   idx     = (iou[1] > iou[0]) ? 1 : 0;   // first-wins tie = argmax
            float max_iou = idx ? iou[1] : iou[0];
            int   o       = 5 * idx;

            float dx = pv[o+0] - tv[o+0], dy = pv[o+1] - tv[o+1];
            float dxy = dx * dx + dy * dy;
            float sw  = sqrtf(pv[o+2]) - sqrtf(tv[o+2]);
            float sh  = sqrtf(pv[o+3]) - sqrtf(tv[o+3]);
            float dwh = sw * sw + sh * sh;
            float dob = (pv[o+4] - max_iou) * (pv[o+4] - max_iou);
            float d4 = pv[4] - tv[4];
            float d9 = pv[9] - tv[9];
            float dnoobj = d4 * d4 + d9 * d9;

            acc += m * (L_COORD * (dxy + dwh) + dob) + nm * L_NOOBJ * dnoobj;
        }

        __syncthreads();   // all LDS reads done before next tile's writes
    }

    // ---- Reduction: wave shuffle -> wsum -> one partial per block
    #pragma unroll
    for (int off = 32; off > 0; off >>= 1)
        acc += __shfl_down(acc, off, 64);

    const int w = tid >> 6, lane = tid & 63;
    if (lane == 0) wsum[w] = acc;
    __syncthreads();
    if (tid == 0) partial[blockIdx.x] = wsum[0] + wsum[1];
}

__global__ __launch_bounds__(256) void yolo_loss_stage2(
    const float* __restrict__ partial,
    float* __restrict__ out)
{
    const int tid = threadIdx.x;
    float s = 0.0f;
    for (int i = tid; i < NBLOCKS; i += 256) s += partial[i];

    #pragma unroll
    for (int off = 32; off > 0; off >>= 1)
        s += __shfl_down(s, off, 64);

    __shared__ float wsum[4];
    int lane = tid & 63;
    int wid  = tid >> 6;
    if (lane == 0) wsum[wid] = s;
    __syncthreads();
    if (tid == 0) {
        out[0] = (wsum[0] + wsum[1] + wsum[2] + wsum[3]) * (1.0f / (float)BATCH);
    }
}

extern "C" void kernel_launch(void* const* d_in, const int* in_sizes, int n_in,
                              void* d_out, int out_size, void* d_ws, size_t ws_size,
                              hipStream_t stream)
{
    const float* pred = (const float*)d_in[0];
    const float* tgt  = (const float*)d_in[1];
    float* out        = (float*)d_out;
    float* partial    = (float*)d_ws;   // 3136 floats = 12.5 KB

    hipLaunchKernelGGL(yolo_loss_stage1, dim3(NBLOCKS), dim3(THREADS), 0, stream,
                       pred, tgt, partial);
    hipLaunchKernelGGL(yolo_loss_stage2, dim3(1), dim3(256), 0, stream,
                       partial, out);
}

// Round 4
// 208.397 us; speedup vs baseline: 1.2220x; 1.2220x over previous
//
#include <hip/hip_runtime.h>

// YOLO loss: S=14, B=2, C=20, N_CH=30, batch=4096
// pred, target: (4096, 14, 14, 30) float32. Output: scalar float32.
//
// R9 = R8 (counted-vmcnt DMA streaming) + full sched_barrier(0) fencing
// around both raw s_barriers (raw s_barrier is NOT a compiler memory fence;
// without fences the scheduler may hoist ds_reads above the barrier or sink
// DMA issues below it -- rule #18 class bug).  R8 run died at infra level
// with no counters; structure audit found no hang mechanism, so resubmit
// hardened.
//
// Theory (unchanged): TCP-return loads pin <=2.4 TB/s at ANY occupancy
// (R0/R2/R4/R7); best-ever is R5's global_load_lds DMA at 2.64 TB/s, but
// R5 drains vmcnt(0) before math (fetch/compute serialized).  Here: double
// buffer, wave0 streams pred / wave1 streams tgt (15 x 1 KiB DMA per tile),
// s_waitcnt vmcnt(15) so the next tile's DMAs stay in flight through math.

#define SDIM 14
#define NCH  30
#define BATCH 4096
#define NCELLS (BATCH * SDIM * SDIM)      // 802816
#define TILE_CELLS 128
#define NTILES (NCELLS / TILE_CELLS)      // 6272, exact
#define GRID 512                          // 2 blocks/CU resident, grid-stride
#define THREADS 128
#define TILE_F4 (TILE_CELLS * NCH / 4)    // 960 float4 per tensor per tile
#define CALLS_PER_TILE (TILE_F4 / 64)     // 15 wave-calls per tensor per tile
#define L_COORD 5.0f
#define L_NOOBJ 0.5f

__device__ __forceinline__ void dma16(void* lds_uniform_base,
                                      const float4* gsrc_lane)
{
    // LDS dest is wave-uniform base; HW writes lane L at base + L*16.
    __builtin_amdgcn_global_load_lds(
        (const __attribute__((address_space(1))) void*)gsrc_lane,
        (__attribute__((address_space(3))) void*)lds_uniform_base,
        16, 0, 0);
}

__global__ __launch_bounds__(THREADS) void yolo_loss_stage1(
    const float* __restrict__ pred,
    const float* __restrict__ tgt,
    float* __restrict__ partial)
{
    // Double buffer: [buf][pred 0..960 | tgt 960..1920] float4 = 30 KiB each.
    __shared__ __align__(16) float4 lds[2][2 * TILE_F4];
    __shared__ float wsum[2];

    const int tid  = threadIdx.x;
    const int w    = tid >> 6;         // wave id: 0 streams pred, 1 streams tgt
    const int lane = tid & 63;

    const float4* gsrc = (w == 0) ? (const float4*)pred : (const float4*)tgt;

    float acc = 0.0f;

    // Prologue: issue tile blockIdx.x into buf 0 (15 x 1 KiB per wave).
    {
        const float4* s = gsrc + (size_t)blockIdx.x * TILE_F4 + lane;
        float4* d = &lds[0][w * TILE_F4];
        #pragma unroll
        for (int j = 0; j < CALLS_PER_TILE; ++j)
            dma16(d + j * 64, s + j * 64);
    }

    int p = 0;
    for (int t = blockIdx.x; t < NTILES; t += GRID) {
        const int tn = t + GRID;
        if (tn < NTILES) {
            // Issue next tile into the other buffer, THEN wait only for the
            // previous 15 (this wave's tile t); next tile's 15 stay in flight.
            const float4* s = gsrc + (size_t)tn * TILE_F4 + lane;
            float4* d = &lds[p ^ 1][w * TILE_F4];
            #pragma unroll
            for (int j = 0; j < CALLS_PER_TILE; ++j)
                dma16(d + j * 64, s + j * 64);
            asm volatile("s_waitcnt vmcnt(15)" ::: "memory");
        } else {
            asm volatile("s_waitcnt vmcnt(0)" ::: "memory");
        }
        __builtin_amdgcn_sched_barrier(0);
        __builtin_amdgcn_s_barrier();      // raw barrier: NO vmcnt drain
        __builtin_amdgcn_sched_barrier(0); // fence: no ds_read hoists above

        // ---- math on buf p: thread tid owns cell tid (128 cells/tile).
        {
            const float* lp = (const float*)&lds[p][0]           + tid * NCH;
            const float* lt = (const float*)&lds[p][TILE_F4]     + tid * NCH;
            float pv[NCH], tv[NCH];
            #pragma unroll
            for (int i = 0; i < NCH / 2; ++i) {
                float2 a = ((const float2*)lp)[i]; pv[2*i] = a.x; pv[2*i+1] = a.y;
                float2 b = ((const float2*)lt)[i]; tv[2*i] = b.x; tv[2*i+1] = b.y;
            }

            const float invS = 1.0f / (float)SDIM;
            float m  = (tv[4] > 0.0f) ? 1.0f : 0.0f;
            float nm = 1.0f - m;

            // target box 0 -> xyxy
            float tcx = tv[0] * invS, tcy = tv[1] * invS;
            float tw  = tv[2],        th  = tv[3];
            float tx1 = tcx - 0.5f * tw, ty1 = tcy - 0.5f * th;
            float tx2 = tcx + 0.5f * tw, ty2 = tcy + 0.5f * th;
            float ta  = (tx2 - tx1) * (ty2 - ty1);

            float iou0, iou1;
            {
                float cx = pv[0] * invS, cy = pv[1] * invS;
                float x1 = cx - 0.5f * pv[2], y1 = cy - 0.5f * pv[3];
                float x2 = cx + 0.5f * pv[2], y2 = cy + 0.5f * pv[3];
                float iw = fmaxf(fminf(x2, tx2) - fmaxf(x1, tx1), 0.0f);
                float ih = fmaxf(fminf(y2, ty2) - fmaxf(y1, ty1), 0.0f);
                float inter = iw * ih;
                float pa = (x2 - x1) * (y2 - y1);
                iou0 = inter / (pa + ta - inter);
            }
            {
                float cx = pv[5] * invS, cy = pv[6] * invS;
                float x1 = cx - 0.5f * pv[7], y1 = cy - 0.5f * pv[8];
                float x2 = cx + 0.5f * pv[7], y2 = cy + 0.5f * pv[8];
                float iw = fmaxf(fminf(x2, tx2) - fmaxf(x1, tx1), 0.0f);
                float ih = fmaxf(fminf(y2, ty2) - fmaxf(y1, ty1), 0.0f);
                float inter = iw * ih;
                float pa = (x2 - x1) * (y2 - y1);
                iou1 = inter / (pa + ta - inter);
            }

            // argmax (first-wins tie = jnp.argmax); scalar selects only,
            // NO runtime-indexed arrays (R7 scratch-spill lesson).
            bool  sel     = (iou1 > iou0);
            float max_iou = sel ? iou1 : iou0;
            float rp0 = sel ? pv[5] : pv[0];
            float rp1 = sel ? pv[6] : pv[1];
            float rp2 = sel ? pv[7] : pv[2];
            float rp3 = sel ? pv[8] : pv[3];
            float rp4 = sel ? pv[9] : pv[4];
            float rt0 = sel ? tv[5] : tv[0];
            float rt1 = sel ? tv[6] : tv[1];
            float rt2 = sel ? tv[7] : tv[2];
            float rt3 = sel ? tv[8] : tv[3];

            float dx = rp0 - rt0, dy = rp1 - rt1;
            float dxy = dx * dx + dy * dy;
            float sw = sqrtf(rp2) - sqrtf(rt2);
            float sh = sqrtf(rp3) - sqrtf(rt3);
            float dwh = sw * sw + sh * sh;
            float dob = (rp4 - max_iou) * (rp4 - max_iou);

            float dcls = 0.0f;
            #pragma unroll
            for (int c = 10; c < NCH; ++c) {
                float d = pv[c] - tv[c];
                dcls = fmaf(d, d, dcls);
            }

            float d4 = pv[4] - tv[4];
            float d9 = pv[9] - tv[9];
            float dnoobj = d4 * d4 + d9 * d9;

            acc += m * (L_COORD * (dxy + dwh) + dob + dcls)
                 + nm * L_NOOBJ * dnoobj;
        }

        // Fence both sides: LDS reads must not sink below, next iteration's
        // DMA issues must not hoist above this barrier.
        __builtin_amdgcn_sched_barrier(0);
        __builtin_amdgcn_s_barrier();
        __builtin_amdgcn_sched_barrier(0);
        p ^= 1;
    }

    // ---- Reduction: wave shuffle -> wsum -> one partial per block
    #pragma unroll
    for (int off = 32; off > 0; off >>= 1)
        acc += __shfl_down(acc, off, 64);

    if (lane == 0) wsum[w] = acc;
    __syncthreads();
    if (tid == 0) partial[blockIdx.x] = wsum[0] + wsum[1];
}

__global__ __launch_bounds__(256) void yolo_loss_stage2(
    const float* __restrict__ partial,
    float* __restrict__ out)
{
    const int tid = threadIdx.x;
    float s = 0.0f;
    for (int i = tid; i < GRID; i += 256) s += partial[i];

    #pragma unroll
    for (int off = 32; off > 0; off >>= 1)
        s += __shfl_down(s, off, 64);

    __shared__ float wsum[4];
    int lane = tid & 63;
    int wid  = tid >> 6;
    if (lane == 0) wsum[wid] = s;
    __syncthreads();
    if (tid == 0) {
        out[0] = (wsum[0] + wsum[1] + wsum[2] + wsum[3]) * (1.0f / (float)BATCH);
    }
}

extern "C" void kernel_launch(void* const* d_in, const int* in_sizes, int n_in,
                              void* d_out, int out_size, void* d_ws, size_t ws_size,
                              hipStream_t stream)
{
    const float* pred = (const float*)d_in[0];
    const float* tgt  = (const float*)d_in[1];
    float* out        = (float*)d_out;
    float* partial    = (float*)d_ws;   // 512 floats = 2 KB

    hipLaunchKernelGGL(yolo_loss_stage1, dim3(GRID), dim3(THREADS), 0, stream,
                       pred, tgt, partial);
    hipLaunchKernelGGL(yolo_loss_stage2, dim3(1), dim3(256), 0, stream,
                       partial, out);
}